// Round 4
// baseline (236.346 us; speedup 1.0000x reference)
//
#include <hip/hip_runtime.h>
#include <hip/hip_bf16.h>

// FeatureAdaption on MI355X: offset = shape @ w_off (1x1), DCNv1 deform conv + ReLU.
// B=8, Cin=Cout=256, H=W=64, G=4, Cg=64, K=3, K2=9, NGK=36, NPIX=32768.
// koff -> float2 sampling positions; kxt -> channels-last bf16 xT[b][g][hw][c];
// kwb -> bf16 weights wB[gk][o][c] XOR-swizzled; kmain: 256out x 256px tile,
// fused bilinear sampling (half-split pipeline) + bf16 MFMA GEMM + ReLU.

#define NPIX 32768
#define NGK  36
#define HW   4096

typedef __attribute__((ext_vector_type(8))) short short8;
typedef __attribute__((ext_vector_type(4))) float f32x4;
typedef unsigned short u16;
typedef unsigned int u32;

__device__ __forceinline__ float bfu_lo(u32 u) {
    union { u32 u; float f; } cv; cv.u = u << 16; return cv.f;
}
__device__ __forceinline__ float bfu_hi(u32 u) {
    union { u32 u; float f; } cv; cv.u = u & 0xFFFF0000u; return cv.f;
}
__device__ __forceinline__ u16 f2bf(float f) {
    union { float f; u32 u; } cv;
    cv.f = f;
    u32 u = cv.u + 0x7FFFu + ((cv.u >> 16) & 1u);
    return (u16)(u >> 16);
}
__device__ __forceinline__ void async_cp16(const void* g, void* l) {
    __builtin_amdgcn_global_load_lds(
        (const __attribute__((address_space(1))) void*)g,
        (__attribute__((address_space(3))) void*)l, 16, 0, 0);
}

// ---------------- Kernel O: sampling positions, float2 [gk][pix] ----------------
__global__ __launch_bounds__(256) void koff(const float* __restrict__ shape,
                                            const float* __restrict__ w_off,
                                            float2* __restrict__ pos) {
    __shared__ float wo[72 * 36];
    int tid = threadIdx.x;
    for (int i = tid; i < 72 * 36; i += 256) wo[i] = w_off[i];
    __syncthreads();

    int pix = blockIdx.x * 256 + tid;
    int b = pix >> 12, hw = pix & 4095;
    int h = hw >> 6, w = hw & 63;

    float s[36];
#pragma unroll
    for (int i = 0; i < 36; ++i) s[i] = shape[((b * 36 + i) << 12) + hw];

    for (int gk = 0; gk < 36; ++gk) {
        float oy = 0.f, ox = 0.f;
        const float* wy = &wo[(gk * 2 + 0) * 36];
        const float* wx = &wo[(gk * 2 + 1) * 36];
#pragma unroll
        for (int i = 0; i < 36; ++i) { oy += s[i] * wy[i]; ox += s[i] * wx[i]; }
        int k = gk % 9;
        pos[gk * NPIX + pix] = make_float2(oy + (float)(k / 3 - 1) + (float)h,
                                           ox + (float)(k % 3 - 1) + (float)w);
    }
}

// ---------------- Kernel X: x (B,256,H,W) fp32 -> xT[b][g][hw][c] bf16 ----------------
__global__ __launch_bounds__(256) void kxt(const float* __restrict__ x,
                                           u16* __restrict__ xT) {
    __shared__ float tile[64][65];
    int tid = threadIdx.x;
    int bg  = blockIdx.x >> 6;          // b*4+g
    int hw0 = (blockIdx.x & 63) << 6;
    int hwo = tid & 63;
#pragma unroll
    for (int i = 0; i < 16; ++i) {
        int c = (tid >> 6) + (i << 2);
        tile[c][hwo] = x[((bg << 6) + c) * HW + hw0 + hwo];
    }
    __syncthreads();
    int hw = tid >> 2;
    int cb4 = (tid & 3) << 4;
    short8 r0, r1;
#pragma unroll
    for (int j = 0; j < 8; ++j) {
        r0[j] = (short)f2bf(tile[cb4 + j][hw]);
        r1[j] = (short)f2bf(tile[cb4 + 8 + j][hw]);
    }
    u16* dst = xT + (((bg << 12) + hw0 + hw) << 6) + cb4;
    *(short8*)dst = r0;
    *(short8*)(dst + 8) = r1;
}

// ---------------- Kernel W: wB[gk][o][c ^ ((o&7)<<3)] = bf16(w_def[o][g*64+c][k]) ----------------
__global__ __launch_bounds__(256) void kwb(const float* __restrict__ w_def,
                                           u16* __restrict__ wB) {
    int idx = blockIdx.x * 256 + threadIdx.x;  // 36*256*64 = 589824
    int c = idx & 63;
    int o = (idx >> 6) & 255;
    int gk = idx >> 14;
    int g = gk / 9, k = gk - g * 9;
    float v = w_def[((o << 8) + (g << 6) + c) * 9 + k];
    wB[(gk << 14) + (o << 6) + (c ^ ((o & 7) << 3))] = f2bf(v);
}

// ---------------- main: 256x256 tile, fused sampling + MFMA GEMM + ReLU ----------------
struct Corner {
    int a00, a01, a10, a11;        // pixel offsets (in 128B px units) within slab
    float w00, w01, w10, w11;
};

__device__ __forceinline__ Corner calc_corner(int gk, int pix, const float2* __restrict__ pos) {
    Corner c;
    float2 p = pos[gk * NPIX + pix];
    float py = p.x, px = p.y;
    float y0f = floorf(py), x0f = floorf(px);
    float fy = py - y0f, fx = px - x0f;
    int y0 = (int)y0f, x0 = (int)x0f;
    int y1 = y0 + 1, x1 = x0 + 1;
    float vy0 = (y0 >= 0 && y0 < 64) ? 1.f : 0.f;
    float vy1 = (y1 >= 0 && y1 < 64) ? 1.f : 0.f;
    float vx0 = (x0 >= 0 && x0 < 64) ? 1.f : 0.f;
    float vx1 = (x1 >= 0 && x1 < 64) ? 1.f : 0.f;
    c.w00 = (1.f - fy) * (1.f - fx) * vy0 * vx0;
    c.w01 = (1.f - fy) * fx * vy0 * vx1;
    c.w10 = fy * (1.f - fx) * vy1 * vx0;
    c.w11 = fy * fx * vy1 * vx1;
    int yc0 = min(max(y0, 0), 63), yc1 = min(max(y1, 0), 63);
    int xc0 = min(max(x0, 0), 63), xc1 = min(max(x1, 0), 63);
    c.a00 = (yc0 << 6) + xc0; c.a01 = (yc0 << 6) + xc1;
    c.a10 = (yc1 << 6) + xc0; c.a11 = (yc1 << 6) + xc1;
    return c;
}

struct GatherH { short8 v[8]; };   // [corner][granule]: 16 channels x 4 corners

__device__ __forceinline__ GatherH gather_half(const u16* __restrict__ sl, const Corner& c) {
    GatherH g;
    g.v[0] = *(const short8*)(sl + (c.a00 << 6));
    g.v[1] = *(const short8*)(sl + (c.a00 << 6) + 8);
    g.v[2] = *(const short8*)(sl + (c.a01 << 6));
    g.v[3] = *(const short8*)(sl + (c.a01 << 6) + 8);
    g.v[4] = *(const short8*)(sl + (c.a10 << 6));
    g.v[5] = *(const short8*)(sl + (c.a10 << 6) + 8);
    g.v[6] = *(const short8*)(sl + (c.a11 << 6));
    g.v[7] = *(const short8*)(sl + (c.a11 << 6) + 8);
    return g;
}

__device__ __forceinline__ void finish_half(const GatherH& gh, const Corner& c,
                                            u16* __restrict__ sVb, int sp, int cgbase) {
#pragma unroll
    for (int gi = 0; gi < 2; ++gi) {
        union { short8 s8; u32 u[4]; } A, Bc, C, D;
        A.s8 = gh.v[gi]; Bc.s8 = gh.v[2 + gi]; C.s8 = gh.v[4 + gi]; D.s8 = gh.v[6 + gi];
        union { u32 u[4]; short8 s8; } R;
#pragma unroll
        for (int j = 0; j < 4; ++j) {
            float lo0 = fmaf(c.w00, bfu_lo(A.u[j]), c.w01 * bfu_lo(Bc.u[j]));
            float lo1 = fmaf(c.w10, bfu_lo(C.u[j]), c.w11 * bfu_lo(D.u[j]));
            float hi0 = fmaf(c.w00, bfu_hi(A.u[j]), c.w01 * bfu_hi(Bc.u[j]));
            float hi1 = fmaf(c.w10, bfu_hi(C.u[j]), c.w11 * bfu_hi(D.u[j]));
            __hip_bfloat162 pk = __float22bfloat162_rn(make_float2(lo0 + lo1, hi0 + hi1));
            union { __hip_bfloat162 b; u32 u; } cv; cv.b = pk;
            R.u[j] = cv.u;
        }
        int cg = cgbase + gi;
        *(short8*)(sVb + (sp << 6) + ((cg ^ (sp & 7)) << 3)) = R.s8;
    }
}

__device__ __forceinline__ void mfma_kc(const u16* __restrict__ Wb, const u16* __restrict__ Vb,
                                        int kc, int lane, int o0, int p0, f32x4 acc[8][4]) {
    int c0 = (kc << 5) + ((lane >> 4) << 3);
    int cs = c0 ^ ((lane & 7) << 3);
    short8 af[8], bfr[4];
#pragma unroll
    for (int of = 0; of < 8; ++of)
        af[of] = *(const short8*)(Wb + ((o0 + (of << 4) + (lane & 15)) << 6) + cs);
#pragma unroll
    for (int pf = 0; pf < 4; ++pf)
        bfr[pf] = *(const short8*)(Vb + ((p0 + (pf << 4) + (lane & 15)) << 6) + cs);
    __builtin_amdgcn_s_setprio(1);
#pragma unroll
    for (int of = 0; of < 8; ++of)
#pragma unroll
        for (int pf = 0; pf < 4; ++pf)
            acc[of][pf] = __builtin_amdgcn_mfma_f32_16x16x32_bf16(
                af[of], bfr[pf], acc[of][pf], 0, 0, 0);
    __builtin_amdgcn_s_setprio(0);
}

__global__ __launch_bounds__(512, 2) void kmain(
    const u16* __restrict__ xT,
    const float2* __restrict__ pos,
    const u16* __restrict__ wB, float* __restrict__ out)
{
    __shared__ __align__(16) u16 sW[2][256 * 64];  // weights tile, 32KB each
    __shared__ __align__(16) u16 sV[2][256 * 64];  // sampled values, 32KB each

    int tid = threadIdx.x;
    int pixbase = blockIdx.x << 8;   // 256 pixels per block (4 rows), same b
    int b = pixbase >> 12;

    int sp = tid & 255;              // sampling: pixel
    int sch = (tid >> 8) << 5;       // sampling: channel base (0 or 32)
    int cg0 = sch >> 3;              // granule base (0 or 4)

    int lane = tid & 63, wid = tid >> 6;
    int o0 = (wid & 1) << 7;         // 2 o-slices of 128
    int p0 = (wid >> 1) << 6;        // 4 px-slices of 64

    f32x4 acc[8][4];
#pragma unroll
    for (int i = 0; i < 8; ++i)
#pragma unroll
        for (int j = 0; j < 4; ++j)
            acc[i][j] = (f32x4){0.f, 0.f, 0.f, 0.f};

    const u16* slabB = xT + ((size_t)b << 20);   // b*4 slabs of 4096px*64ch

    // ---- prologue: stage W0 + fully sample tap 0 ----
    {
#pragma unroll
        for (int r = 0; r < 4; ++r)
            async_cp16(wB + (r << 12) + (tid << 3), &sW[0][(r << 12) + (tid << 3)]);
        Corner c = calc_corner(0, pixbase + sp, pos);
        const u16* sl = slabB + sch;             // g=0
        GatherH gA = gather_half(sl, c);
        GatherH gB = gather_half(sl + 16, c);
        finish_half(gA, c, sV[0], sp, cg0);
        finish_half(gB, c, sV[0], sp, cg0 + 2);
    }
    __syncthreads();

    for (int t = 0; t < NGK; ++t) {
        int cb = t & 1, nb = cb ^ 1;
        bool hn = (t + 1 < NGK);
        Corner c;
        const u16* sl = nullptr;
        GatherH gA, gB;
        if (hn) {
            const u16* wsrc = wB + ((t + 1) << 14);
#pragma unroll
            for (int r = 0; r < 4; ++r)
                async_cp16(wsrc + (r << 12) + (tid << 3), &sW[nb][(r << 12) + (tid << 3)]);
            int g = (t + 1) / 9;
            c = calc_corner(t + 1, pixbase + sp, pos);
            sl = slabB + (g << 18) + sch;
            gA = gather_half(sl, c);             // issue half-A gathers
        }

        mfma_kc(sW[cb], sV[cb], 0, lane, o0, p0, acc);

        if (hn) {
            gB = gather_half(sl + 16, c);        // issue half-B gathers
            finish_half(gA, c, sV[nb], sp, cg0); // finish half-A (covered by kc0)
        }

        mfma_kc(sW[cb], sV[cb], 1, lane, o0, p0, acc);

        if (hn) finish_half(gB, c, sV[nb], sp, cg0 + 2);
        __syncthreads();
    }

    // ---- epilogue: ReLU + store ----
    int hwb = (pixbase & 4095) + p0;
    int obase = (b << 8) + o0 + ((lane >> 4) << 2);
#pragma unroll
    for (int of = 0; of < 8; ++of) {
#pragma unroll
        for (int pf = 0; pf < 4; ++pf) {
            float* op = out + ((obase + (of << 4)) << 12) + hwb + (pf << 4) + (lane & 15);
#pragma unroll
            for (int r = 0; r < 4; ++r)
                op[r << 12] = fmaxf(acc[of][pf][r], 0.f);
        }
    }
}

extern "C" void kernel_launch(void* const* d_in, const int* in_sizes, int n_in,
                              void* d_out, int out_size, void* d_ws, size_t ws_size,
                              hipStream_t stream) {
    const float* x     = (const float*)d_in[0];
    const float* shape = (const float*)d_in[1];
    const float* w_off = (const float*)d_in[2];
    const float* w_def = (const float*)d_in[3];
    float* out = (float*)d_out;

    float2* pos = (float2*)d_ws;                      // 36*32768 float2 = 9.4 MB
    u16*    wB  = (u16*)(pos + NGK * NPIX);           // 36*256*64 bf16 = 1.18 MB
    u16*    xT  = wB + NGK * 256 * 64;                // 8*4*4096*64 bf16 = 16.8 MB

    koff<<<NPIX / 256, 256, 0, stream>>>(shape, w_off, pos);
    kxt<<<2048, 256, 0, stream>>>(x, xT);
    kwb<<<2304, 256, 0, stream>>>(w_def, wB);
    kmain<<<NPIX / 256, 512, 0, stream>>>(xT, pos, wB, out);
}

// Round 5
// 151.293 us; speedup vs baseline: 1.5622x; 1.5622x over previous
//
#include <hip/hip_runtime.h>
#include <hip/hip_bf16.h>

// FeatureAdaption on MI355X: offset = shape @ w_off (1x1), DCNv1 deform conv + ReLU.
// B=8, Cin=Cout=256, H=W=64, G=4, Cg=64, K=3, K2=9, NGK=36, NPIX=32768.
// kprep (merged): pos (float2), channels-last bf16 xT[b][g][hw][c], swizzled bf16 wB.
// kmain: 256o x 64px tile, 512 blocks (2/CU), fused bilinear sampling + MFMA GEMM,
// 1-tap-ahead gather pipeline pinned with sched_barrier, counted-vmcnt raw barriers.

#define NPIX 32768
#define NGK  36
#define HW   4096

typedef __attribute__((ext_vector_type(8))) short short8;
typedef __attribute__((ext_vector_type(4))) float f32x4;
typedef unsigned short u16;
typedef unsigned int u32;

__device__ __forceinline__ float bfu_lo(u32 u) {
    union { u32 u; float f; } cv; cv.u = u << 16; return cv.f;
}
__device__ __forceinline__ float bfu_hi(u32 u) {
    union { u32 u; float f; } cv; cv.u = u & 0xFFFF0000u; return cv.f;
}
__device__ __forceinline__ u16 f2bf(float f) {
    union { float f; u32 u; } cv;
    cv.f = f;
    u32 u = cv.u + 0x7FFFu + ((cv.u >> 16) & 1u);
    return (u16)(u >> 16);
}
__device__ __forceinline__ void async_cp16(const void* g, void* l) {
    __builtin_amdgcn_global_load_lds(
        (const __attribute__((address_space(1))) void*)g,
        (__attribute__((address_space(3))) void*)l, 16, 0, 0);
}

// ---------------- kprep: koff (128 blks) + kxt (2048 blks) + kwb (2304 blks) ----------------
__global__ __launch_bounds__(256) void kprep(const float* __restrict__ x,
                                             const float* __restrict__ shape,
                                             const float* __restrict__ w_off,
                                             const float* __restrict__ w_def,
                                             float2* __restrict__ pos,
                                             u16* __restrict__ xT,
                                             u16* __restrict__ wB) {
    __shared__ __align__(16) float smem[64 * 65];
    int tid = threadIdx.x;
    int blk = blockIdx.x;

    if (blk < 2048) {
        // ---- kxt: x (B,256,H,W) fp32 -> xT[b][g][hw][c] bf16 ----
        float (*tile)[65] = (float (*)[65])smem;
        int bg  = blk >> 6;
        int hw0 = (blk & 63) << 6;
        int hwo = tid & 63;
#pragma unroll
        for (int i = 0; i < 16; ++i) {
            int c = (tid >> 6) + (i << 2);
            tile[c][hwo] = x[((bg << 6) + c) * HW + hw0 + hwo];
        }
        __syncthreads();
        int hw = tid >> 2;
        int cb4 = (tid & 3) << 4;
        short8 r0, r1;
#pragma unroll
        for (int j = 0; j < 8; ++j) {
            r0[j] = (short)f2bf(tile[cb4 + j][hw]);
            r1[j] = (short)f2bf(tile[cb4 + 8 + j][hw]);
        }
        u16* dst = xT + (((bg << 12) + hw0 + hw) << 6) + cb4;
        *(short8*)dst = r0;
        *(short8*)(dst + 8) = r1;
    } else if (blk < 4352) {
        // ---- kwb: wB[gk][o][c ^ ((o&7)<<3)] = bf16(w_def[o][g*64+c][k]) ----
        int idx = (blk - 2048) * 256 + tid;
        int c = idx & 63;
        int o = (idx >> 6) & 255;
        int gk = idx >> 14;
        int g = gk / 9, k = gk - g * 9;
        float v = w_def[((o << 8) + (g << 6) + c) * 9 + k];
        wB[(gk << 14) + (o << 6) + (c ^ ((o & 7) << 3))] = f2bf(v);
    } else {
        // ---- koff: sampling positions float2 [gk][pix] ----
        float* wo = smem;  // 72*36 = 2592 floats
        for (int i = tid; i < 72 * 36; i += 256) wo[i] = w_off[i];
        __syncthreads();
        int pix = (blk - 4352) * 256 + tid;
        int b = pix >> 12, hw = pix & 4095;
        int h = hw >> 6, w = hw & 63;
        float s[36];
#pragma unroll
        for (int i = 0; i < 36; ++i) s[i] = shape[((b * 36 + i) << 12) + hw];
        for (int gk = 0; gk < 36; ++gk) {
            float oy = 0.f, ox = 0.f;
            const float* wy = &wo[(gk * 2 + 0) * 36];
            const float* wx = &wo[(gk * 2 + 1) * 36];
#pragma unroll
            for (int i = 0; i < 36; ++i) { oy += s[i] * wy[i]; ox += s[i] * wx[i]; }
            int k = gk % 9;
            pos[gk * NPIX + pix] = make_float2(oy + (float)(k / 3 - 1) + (float)h,
                                               ox + (float)(k % 3 - 1) + (float)w);
        }
    }
}

// ---------------- main: fused sampling + MFMA GEMM + ReLU ----------------
struct Samp {
    short8 v00, v01, v10, v11;
    float w00, w01, w10, w11;
    int dst;
};

__device__ __forceinline__ Samp sample_issue_p(float2 p, const u16* __restrict__ slab,
                                               int sp, int sck) {
    Samp s;
    float py = p.x, px = p.y;
    float y0f = floorf(py), x0f = floorf(px);
    float fy = py - y0f, fx = px - x0f;
    int y0 = (int)y0f, x0 = (int)x0f;
    int y1 = y0 + 1, x1 = x0 + 1;
    float vy0 = (y0 >= 0 && y0 < 64) ? 1.f : 0.f;
    float vy1 = (y1 >= 0 && y1 < 64) ? 1.f : 0.f;
    float vx0 = (x0 >= 0 && x0 < 64) ? 1.f : 0.f;
    float vx1 = (x1 >= 0 && x1 < 64) ? 1.f : 0.f;
    s.w00 = (1.f - fy) * (1.f - fx) * vy0 * vx0;
    s.w01 = (1.f - fy) * fx * vy0 * vx1;
    s.w10 = fy * (1.f - fx) * vy1 * vx0;
    s.w11 = fy * fx * vy1 * vx1;
    int yc0 = min(max(y0, 0), 63), yc1 = min(max(y1, 0), 63);
    int xc0 = min(max(x0, 0), 63), xc1 = min(max(x1, 0), 63);
    const u16* base = slab + (sck << 3);
    s.v00 = *(const short8*)(base + ((((yc0 << 6) + xc0)) << 6));
    s.v01 = *(const short8*)(base + ((((yc0 << 6) + xc1)) << 6));
    s.v10 = *(const short8*)(base + ((((yc1 << 6) + xc0)) << 6));
    s.v11 = *(const short8*)(base + ((((yc1 << 6) + xc1)) << 6));
    s.dst = (sp << 6) + ((sck ^ (sp & 7)) << 3);   // XOR-swizzled slot
    return s;
}

__device__ __forceinline__ void sample_finish(const Samp& s, u16* __restrict__ sVb) {
    union { short8 s8; u32 u[4]; } A, Bc, C, D;
    A.s8 = s.v00; Bc.s8 = s.v01; C.s8 = s.v10; D.s8 = s.v11;
    union { u32 u[4]; short8 s8; } R;
#pragma unroll
    for (int j = 0; j < 4; ++j) {
        float lo0 = fmaf(s.w00, bfu_lo(A.u[j]), s.w01 * bfu_lo(Bc.u[j]));
        float lo1 = fmaf(s.w10, bfu_lo(C.u[j]), s.w11 * bfu_lo(D.u[j]));
        float hi0 = fmaf(s.w00, bfu_hi(A.u[j]), s.w01 * bfu_hi(Bc.u[j]));
        float hi1 = fmaf(s.w10, bfu_hi(C.u[j]), s.w11 * bfu_hi(D.u[j]));
        __hip_bfloat162 pk = __float22bfloat162_rn(make_float2(lo0 + lo1, hi0 + hi1));
        union { __hip_bfloat162 b; u32 u; } cv; cv.b = pk;
        R.u[j] = cv.u;
    }
    *(short8*)(sVb + s.dst) = R.s8;
}

__device__ __forceinline__ void mfma_phase(
    const u16* __restrict__ Wb, const u16* __restrict__ Vb,
    int lane, int o0, int p0, f32x4 acc[4][2])
{
    __builtin_amdgcn_s_setprio(1);
#pragma unroll
    for (int kc = 0; kc < 2; ++kc) {
        int c0 = (kc << 5) + ((lane >> 4) << 3);
        int cs = c0 ^ ((lane & 7) << 3);
        short8 af[4], bfr[2];
#pragma unroll
        for (int of = 0; of < 4; ++of) {
            int o = o0 + (of << 4) + (lane & 15);
            af[of] = *(const short8*)(Wb + (o << 6) + cs);
        }
#pragma unroll
        for (int pf = 0; pf < 2; ++pf) {
            int p = p0 + (pf << 4) + (lane & 15);
            bfr[pf] = *(const short8*)(Vb + (p << 6) + cs);
        }
#pragma unroll
        for (int of = 0; of < 4; ++of)
#pragma unroll
            for (int pf = 0; pf < 2; ++pf)
                acc[of][pf] = __builtin_amdgcn_mfma_f32_16x16x32_bf16(
                    af[of], bfr[pf], acc[of][pf], 0, 0, 0);
    }
    __builtin_amdgcn_s_setprio(0);
}

__global__ __launch_bounds__(512, 4) void kmain(
    const u16* __restrict__ xT,
    const float2* __restrict__ pos,
    const u16* __restrict__ wB, float* __restrict__ out)
{
    __shared__ __align__(16) u16 sW[2][256 * 64];  // weights, 32KB each
    __shared__ __align__(16) u16 sV[2][64 * 64];   // sampled values, 8KB each

    int tid = threadIdx.x;
    int pixbase = blockIdx.x << 6;   // 64 pixels per block
    int b = pixbase >> 12;

    int sp = tid >> 3, sck = tid & 7;        // sampling roles: 64px x 8 chunks
    int lane = tid & 63, wid = tid >> 6;     // compute roles
    int o0 = (wid & 3) << 6;                 // 4 o-slices of 64
    int p0 = (wid >> 2) << 5;                // 2 px-slices of 32

    int pixw = pixbase + sp;
    const u16* slabB = xT + ((size_t)b << 20);   // 4 g-slabs of 4096px*64ch

    f32x4 acc[4][2];
#pragma unroll
    for (int i = 0; i < 4; ++i)
#pragma unroll
        for (int j = 0; j < 2; ++j)
            acc[i][j] = (f32x4){0.f, 0.f, 0.f, 0.f};

    Samp sA, sB;
    float2 posE, posO;

    // ---- prologue: stage W0; sample+finish tap0; issue tap1; preload pos[2],pos[3] ----
    {
#pragma unroll
        for (int r = 0; r < 4; ++r)
            async_cp16(wB + (r << 12) + (tid << 3), &sW[0][(r << 12) + (tid << 3)]);
        float2 pv0 = pos[pixw];                      // tap0
        Samp s0 = sample_issue_p(pv0, slabB, sp, sck);
        sample_finish(s0, sV[0]);
        float2 pv1 = pos[NPIX + pixw];               // tap1
        sA = sample_issue_p(pv1, slabB, sp, sck);
        posE = pos[2 * NPIX + pixw];
        posO = pos[3 * NPIX + pixw];
        asm volatile("s_waitcnt vmcnt(6) lgkmcnt(0)" ::: "memory");
        __builtin_amdgcn_s_barrier();
        __builtin_amdgcn_sched_barrier(0);
    }

    // body(t): stage sW(t+1); issue gathers(t+2) from preloaded pos; prefetch pos(t+4);
    // MFMA on tap t; finish samples(t+1); counted-wait + raw barrier.
#define TAP_FAST(T, SFIN, SISS, PREG)                                            \
    {                                                                            \
        const int t_ = (T);                                                      \
        int cb = t_ & 1, nb = cb ^ 1;                                            \
        const u16* wsrc = wB + ((t_ + 1) << 14);                                 \
        _Pragma("unroll")                                                        \
        for (int r = 0; r < 4; ++r)                                              \
            async_cp16(wsrc + (r << 12) + (tid << 3),                            \
                       &sW[nb][(r << 12) + (tid << 3)]);                         \
        __builtin_amdgcn_sched_barrier(0);                                       \
        SISS = sample_issue_p(PREG, slabB + (((t_ + 2) / 9) << 18), sp, sck);    \
        if (t_ + 4 < NGK) PREG = pos[(t_ + 4) * NPIX + pixw];                    \
        __builtin_amdgcn_sched_barrier(0);                                       \
        mfma_phase(sW[cb], sV[cb], lane, o0, p0, acc);                           \
        sample_finish(SFIN, sV[nb]);                                             \
        asm volatile("s_waitcnt vmcnt(1) lgkmcnt(0)" ::: "memory");              \
        __builtin_amdgcn_s_barrier();                                            \
        __builtin_amdgcn_sched_barrier(0);                                       \
    }

    for (int t = 0; t < 34; t += 2) {
        TAP_FAST(t,     sA, sB, posE)
        TAP_FAST(t + 1, sB, sA, posO)
    }
#undef TAP_FAST

    // ---- t=34: stage W35, MFMA tap34, finish tap35 samples ----
    {
#pragma unroll
        for (int r = 0; r < 4; ++r)
            async_cp16(wB + (35 << 14) + (r << 12) + (tid << 3),
                       &sW[1][(r << 12) + (tid << 3)]);
        mfma_phase(sW[0], sV[0], lane, o0, p0, acc);
        sample_finish(sA, sV[1]);
        __syncthreads();
    }
    // ---- t=35 ----
    mfma_phase(sW[1], sV[1], lane, o0, p0, acc);

    // ---- epilogue: ReLU + store ----
    int hwb = (pixbase & 4095) + p0;
    int obase = (b << 8) + o0 + ((lane >> 4) << 2);
#pragma unroll
    for (int of = 0; of < 4; ++of) {
#pragma unroll
        for (int pf = 0; pf < 2; ++pf) {
            float* op = out + ((obase + (of << 4)) << 12) + hwb + (pf << 4) + (lane & 15);
#pragma unroll
            for (int r = 0; r < 4; ++r)
                op[r << 12] = fmaxf(acc[of][pf][r], 0.f);
        }
    }
}

extern "C" void kernel_launch(void* const* d_in, const int* in_sizes, int n_in,
                              void* d_out, int out_size, void* d_ws, size_t ws_size,
                              hipStream_t stream) {
    const float* x     = (const float*)d_in[0];
    const float* shape = (const float*)d_in[1];
    const float* w_off = (const float*)d_in[2];
    const float* w_def = (const float*)d_in[3];
    float* out = (float*)d_out;

    float2* pos = (float2*)d_ws;                      // 36*32768 float2 = 9.4 MB
    u16*    wB  = (u16*)(pos + NGK * NPIX);           // 36*256*64 bf16 = 1.18 MB
    u16*    xT  = wB + NGK * 256 * 64;                // 8*4*4096*64 bf16 = 16.8 MB

    kprep<<<4480, 256, 0, stream>>>(x, shape, w_off, w_def, pos, xT, wB);
    kmain<<<NPIX / 64, 512, 0, stream>>>(xT, pos, wB, out);
}

// Round 6
// 136.572 us; speedup vs baseline: 1.7306x; 1.1078x over previous
//
#include <hip/hip_runtime.h>
#include <hip/hip_bf16.h>

// FeatureAdaption on MI355X: offset = shape @ w_off (1x1), DCNv1 deform conv + ReLU.
// B=8, Cin=Cout=256, H=W=64, G=4, Cg=64, K=3, K2=9, NGK=36, NPIX=32768.
// kprep (merged): pos (float2), channels-last bf16 xT[b][g][hw][c], linear bf16 wB.
// kmain: 256o x 64px tile, 512 blocks (2/CU). Weights: global->register fragments,
// one tap ahead (no weight LDS at all). Samples: within-tap issue->MFMA->finish.
// LDS = sV double-buffer only (16 KB).

#define NPIX 32768
#define NGK  36
#define HW   4096
#define WSTRIDE 16384   // u16 elements per tap in wB (256 o * 64 c)

typedef __attribute__((ext_vector_type(8))) short short8;
typedef __attribute__((ext_vector_type(4))) float f32x4;
typedef unsigned short u16;
typedef unsigned int u32;

__device__ __forceinline__ float bfu_lo(u32 u) {
    union { u32 u; float f; } cv; cv.u = u << 16; return cv.f;
}
__device__ __forceinline__ float bfu_hi(u32 u) {
    union { u32 u; float f; } cv; cv.u = u & 0xFFFF0000u; return cv.f;
}
__device__ __forceinline__ u16 f2bf(float f) {
    union { float f; u32 u; } cv;
    cv.f = f;
    u32 u = cv.u + 0x7FFFu + ((cv.u >> 16) & 1u);
    return (u16)(u >> 16);
}

// ---------------- kprep: kxt (2048 blks) + kwb (2304 blks) + koff (128 blks) ----------------
__global__ __launch_bounds__(256) void kprep(const float* __restrict__ x,
                                             const float* __restrict__ shape,
                                             const float* __restrict__ w_off,
                                             const float* __restrict__ w_def,
                                             float2* __restrict__ pos,
                                             u16* __restrict__ xT,
                                             u16* __restrict__ wB) {
    __shared__ __align__(16) float smem[64 * 65];
    int tid = threadIdx.x;
    int blk = blockIdx.x;

    if (blk < 2048) {
        // ---- kxt: x (B,256,H,W) fp32 -> xT[b][g][hw][c] bf16 ----
        float (*tile)[65] = (float (*)[65])smem;
        int bg  = blk >> 6;
        int hw0 = (blk & 63) << 6;
        int hwo = tid & 63;
#pragma unroll
        for (int i = 0; i < 16; ++i) {
            int c = (tid >> 6) + (i << 2);
            tile[c][hwo] = x[((bg << 6) + c) * HW + hw0 + hwo];
        }
        __syncthreads();
        int hw = tid >> 2;
        int cb4 = (tid & 3) << 4;
        short8 r0, r1;
#pragma unroll
        for (int j = 0; j < 8; ++j) {
            r0[j] = (short)f2bf(tile[cb4 + j][hw]);
            r1[j] = (short)f2bf(tile[cb4 + 8 + j][hw]);
        }
        u16* dst = xT + (((bg << 12) + hw0 + hw) << 6) + cb4;
        *(short8*)dst = r0;
        *(short8*)(dst + 8) = r1;
    } else if (blk < 4352) {
        // ---- kwb: wB[gk][o][c] = bf16(w_def[o][g*64+c][k])  (linear, no swizzle) ----
        int idx = (blk - 2048) * 256 + tid;
        int c = idx & 63;
        int o = (idx >> 6) & 255;
        int gk = idx >> 14;
        int g = gk / 9, k = gk - g * 9;
        float v = w_def[((o << 8) + (g << 6) + c) * 9 + k];
        wB[(gk << 14) + (o << 6) + c] = f2bf(v);
    } else {
        // ---- koff: sampling positions float2 [gk][pix] ----
        float* wo = smem;  // 72*36 floats
        for (int i = tid; i < 72 * 36; i += 256) wo[i] = w_off[i];
        __syncthreads();
        int pix = (blk - 4352) * 256 + tid;
        int b = pix >> 12, hw = pix & 4095;
        int h = hw >> 6, w = hw & 63;
        float s[36];
#pragma unroll
        for (int i = 0; i < 36; ++i) s[i] = shape[((b * 36 + i) << 12) + hw];
        for (int gk = 0; gk < 36; ++gk) {
            float oy = 0.f, ox = 0.f;
            const float* wy = &wo[(gk * 2 + 0) * 36];
            const float* wx = &wo[(gk * 2 + 1) * 36];
#pragma unroll
            for (int i = 0; i < 36; ++i) { oy += s[i] * wy[i]; ox += s[i] * wx[i]; }
            int k = gk % 9;
            pos[gk * NPIX + pix] = make_float2(oy + (float)(k / 3 - 1) + (float)h,
                                               ox + (float)(k % 3 - 1) + (float)w);
        }
    }
}

// ---------------- main: fused sampling + MFMA GEMM + ReLU ----------------
struct Samp {
    short8 v00, v01, v10, v11;
    float w00, w01, w10, w11;
    int dst;
};

__device__ __forceinline__ Samp sample_issue_p(float2 p, const u16* __restrict__ slab,
                                               int sp, int sck) {
    Samp s;
    float py = p.x, px = p.y;
    float y0f = floorf(py), x0f = floorf(px);
    float fy = py - y0f, fx = px - x0f;
    int y0 = (int)y0f, x0 = (int)x0f;
    int y1 = y0 + 1, x1 = x0 + 1;
    float vy0 = (y0 >= 0 && y0 < 64) ? 1.f : 0.f;
    float vy1 = (y1 >= 0 && y1 < 64) ? 1.f : 0.f;
    float vx0 = (x0 >= 0 && x0 < 64) ? 1.f : 0.f;
    float vx1 = (x1 >= 0 && x1 < 64) ? 1.f : 0.f;
    s.w00 = (1.f - fy) * (1.f - fx) * vy0 * vx0;
    s.w01 = (1.f - fy) * fx * vy0 * vx1;
    s.w10 = fy * (1.f - fx) * vy1 * vx0;
    s.w11 = fy * fx * vy1 * vx1;
    int yc0 = min(max(y0, 0), 63), yc1 = min(max(y1, 0), 63);
    int xc0 = min(max(x0, 0), 63), xc1 = min(max(x1, 0), 63);
    const u16* base = slab + (sck << 3);
    s.v00 = *(const short8*)(base + (((yc0 << 6) + xc0) << 6));
    s.v01 = *(const short8*)(base + (((yc0 << 6) + xc1) << 6));
    s.v10 = *(const short8*)(base + (((yc1 << 6) + xc0) << 6));
    s.v11 = *(const short8*)(base + (((yc1 << 6) + xc1) << 6));
    s.dst = (sp << 6) + ((sck ^ (sp & 7)) << 3);   // XOR-swizzled slot
    return s;
}

__device__ __forceinline__ void sample_finish(const Samp& s, u16* __restrict__ sVb) {
    union { short8 s8; u32 u[4]; } A, Bc, C, D;
    A.s8 = s.v00; Bc.s8 = s.v01; C.s8 = s.v10; D.s8 = s.v11;
    union { u32 u[4]; short8 s8; } R;
#pragma unroll
    for (int j = 0; j < 4; ++j) {
        float lo0 = fmaf(s.w00, bfu_lo(A.u[j]), s.w01 * bfu_lo(Bc.u[j]));
        float lo1 = fmaf(s.w10, bfu_lo(C.u[j]), s.w11 * bfu_lo(D.u[j]));
        float hi0 = fmaf(s.w00, bfu_hi(A.u[j]), s.w01 * bfu_hi(Bc.u[j]));
        float hi1 = fmaf(s.w10, bfu_hi(C.u[j]), s.w11 * bfu_hi(D.u[j]));
        __hip_bfloat162 pk = __float22bfloat162_rn(make_float2(lo0 + lo1, hi0 + hi1));
        union { __hip_bfloat162 b; u32 u; } cv; cv.b = pk;
        R.u[j] = cv.u;
    }
    *(short8*)(sVb + s.dst) = R.s8;
}

// MFMA over one tap: A-fragments (weights) already in registers, B from sV LDS.
__device__ __forceinline__ void mfma_phase(const short8 wcur[4], const u16* __restrict__ Vb,
                                           int lane, f32x4 acc[2][4]) {
    __builtin_amdgcn_s_setprio(1);
#pragma unroll
    for (int kc = 0; kc < 2; ++kc) {
        int cs = ((kc << 5) + ((lane >> 4) << 3)) ^ ((lane & 7) << 3);
        short8 bfr[4];
#pragma unroll
        for (int pf = 0; pf < 4; ++pf)
            bfr[pf] = *(const short8*)(Vb + (((pf << 4) + (lane & 15)) << 6) + cs);
#pragma unroll
        for (int of = 0; of < 2; ++of)
#pragma unroll
            for (int pf = 0; pf < 4; ++pf)
                acc[of][pf] = __builtin_amdgcn_mfma_f32_16x16x32_bf16(
                    wcur[of * 2 + kc], bfr[pf], acc[of][pf], 0, 0, 0);
    }
    __builtin_amdgcn_s_setprio(0);
}

__global__ __launch_bounds__(512, 4) void kmain(
    const u16* __restrict__ xT,
    const float2* __restrict__ pos,
    const u16* __restrict__ wB, float* __restrict__ out)
{
    __shared__ __align__(16) u16 sV[2][64 * 64];   // sampled values, 8KB each

    int tid = threadIdx.x;
    int pixbase = blockIdx.x << 6;   // 64 pixels per block
    int b = pixbase >> 12;

    int sp = tid >> 3, sck = tid & 7;        // sampling roles: 64px x 8 chunks
    int lane = tid & 63, wid = tid >> 6;     // compute roles
    int o0 = wid << 5;                       // 8 o-slices of 32 (no p-split)

    int pixw = pixbase + sp;
    const u16* slabB = xT + ((size_t)b << 20);   // 4 g-slabs of 4096px*64ch

    // per-lane weight fragment offset (u16 elems): o = o0+(lane&15)(+of*16), cgran = lane>>4
    int wlofs = ((o0 + (lane & 15)) << 6) + ((lane >> 4) << 3);

    f32x4 acc[2][4];
#pragma unroll
    for (int i = 0; i < 2; ++i)
#pragma unroll
        for (int j = 0; j < 4; ++j)
            acc[i][j] = (f32x4){0.f, 0.f, 0.f, 0.f};

    short8 wC[4], wN[4];   // [of*2+kc] weight fragments, current / next tap
    Samp s;
    float2 pv;

    // ---- prologue: weights tap0 -> wC; sample+finish tap0; pos for tap1 ----
    {
        const u16* w0 = wB + wlofs;
        wC[0] = *(const short8*)(w0);            // of0 kc0
        wC[1] = *(const short8*)(w0 + 32);       // of0 kc1
        wC[2] = *(const short8*)(w0 + 1024);     // of1 kc0
        wC[3] = *(const short8*)(w0 + 1056);     // of1 kc1
        float2 pv0 = pos[pixw];
        Samp s0 = sample_issue_p(pv0, slabB, sp, sck);
        sample_finish(s0, sV[0]);
        pv = pos[NPIX + pixw];
        __syncthreads();
    }

    // body(t): prefetch weights(t+1)->WNXT; issue gathers(t+1); prefetch pos(t+2);
    // MFMA(t) with WCUR + sV[t&1]; finish(t+1) -> sV[(t&1)^1]; barrier.
#define TAP_BODY(T, WCUR, WNXT)                                                  \
    {                                                                            \
        const int t_ = (T);                                                      \
        const u16* wn = wB + (t_ + 1) * WSTRIDE + wlofs;                         \
        WNXT[0] = *(const short8*)(wn);                                          \
        WNXT[1] = *(const short8*)(wn + 32);                                     \
        WNXT[2] = *(const short8*)(wn + 1024);                                   \
        WNXT[3] = *(const short8*)(wn + 1056);                                   \
        s = sample_issue_p(pv, slabB + (((t_ + 1) / 9) << 18), sp, sck);         \
        pv = pos[(t_ + 2) * NPIX + pixw];                                        \
        __builtin_amdgcn_sched_barrier(0);                                       \
        mfma_phase(WCUR, sV[t_ & 1], lane, acc);                                 \
        sample_finish(s, sV[(t_ & 1) ^ 1]);                                      \
        __syncthreads();                                                         \
    }

    for (int t = 0; t < 34; t += 2) {
        TAP_BODY(t,     wC, wN)
        TAP_BODY(t + 1, wN, wC)
    }
#undef TAP_BODY

    // ---- t=34: uses wC (loaded in body 33); prefetch tap35 -> wN; finish 35 ----
    {
        const u16* wn = wB + 35 * WSTRIDE + wlofs;
        wN[0] = *(const short8*)(wn);
        wN[1] = *(const short8*)(wn + 32);
        wN[2] = *(const short8*)(wn + 1024);
        wN[3] = *(const short8*)(wn + 1056);
        s = sample_issue_p(pv, slabB + (3 << 18), sp, sck);
        __builtin_amdgcn_sched_barrier(0);
        mfma_phase(wC, sV[0], lane, acc);
        sample_finish(s, sV[1]);
        __syncthreads();
    }
    // ---- t=35 ----
    mfma_phase(wN, sV[1], lane, acc);

    // ---- epilogue: ReLU + store ----
    int hwb = pixbase & 4095;
    int obase = (b << 8) + o0 + ((lane >> 4) << 2);
#pragma unroll
    for (int of = 0; of < 2; ++of) {
#pragma unroll
        for (int pf = 0; pf < 4; ++pf) {
            float* op = out + ((obase + (of << 4)) << 12) + hwb + (pf << 4) + (lane & 15);
#pragma unroll
            for (int r = 0; r < 4; ++r)
                op[r << 12] = fmaxf(acc[of][pf][r], 0.f);
        }
    }
}

extern "C" void kernel_launch(void* const* d_in, const int* in_sizes, int n_in,
                              void* d_out, int out_size, void* d_ws, size_t ws_size,
                              hipStream_t stream) {
    const float* x     = (const float*)d_in[0];
    const float* shape = (const float*)d_in[1];
    const float* w_off = (const float*)d_in[2];
    const float* w_def = (const float*)d_in[3];
    float* out = (float*)d_out;

    float2* pos = (float2*)d_ws;                      // 36*32768 float2 = 9.4 MB
    u16*    wB  = (u16*)(pos + NGK * NPIX);           // 36*256*64 bf16 = 1.18 MB
    u16*    xT  = wB + NGK * 256 * 64;                // 8*4*4096*64 bf16 = 16.8 MB

    kprep<<<4480, 256, 0, stream>>>(x, shape, w_off, w_def, pos, xT, wB);
    kmain<<<NPIX / 64, 512, 0, stream>>>(xT, pos, wB, out);
}

// Round 7
// 101.328 us; speedup vs baseline: 2.3325x; 1.3478x over previous
//
#include <hip/hip_runtime.h>
#include <hip/hip_bf16.h>

// FeatureAdaption on MI355X: offset = shape @ w_off (1x1), DCNv1 deform conv + ReLU.
// B=8, Cin=Cout=256, H=W=64, G=4, Cg=64, K=3, K2=9, NGK=36, NPIX=32768.
// kprep (merged): pos (float2), channels-last bf16 xT[b][g][hw][c],
// FRAGMENT-MAJOR bf16 weights wF[t][wid][of][kc][lane][8] (coalesced frag loads).
// kmain: 256o x 64px tile, 512 blocks (2/CU). Weights: global->register fragments,
// one tap ahead, loads fully coalesced. Samples: within-tap issue->MFMA->finish.
// LDS = sV double-buffer only (16 KB).

#define NPIX 32768
#define NGK  36
#define HW   4096
#define WSTRIDE 16384   // u16 elements per tap in wF (8 wid * 2 of * 2 kc * 64 lane * 8)

typedef __attribute__((ext_vector_type(8))) short short8;
typedef __attribute__((ext_vector_type(4))) float f32x4;
typedef unsigned short u16;
typedef unsigned int u32;

__device__ __forceinline__ float bfu_lo(u32 u) {
    union { u32 u; float f; } cv; cv.u = u << 16; return cv.f;
}
__device__ __forceinline__ float bfu_hi(u32 u) {
    union { u32 u; float f; } cv; cv.u = u & 0xFFFF0000u; return cv.f;
}
__device__ __forceinline__ u16 f2bf(float f) {
    union { float f; u32 u; } cv;
    cv.f = f;
    u32 u = cv.u + 0x7FFFu + ((cv.u >> 16) & 1u);
    return (u16)(u >> 16);
}

// ---------------- kprep: kxt (2048 blks) + kwb (2304 blks) + koff (128 blks) ----------------
__global__ __launch_bounds__(256) void kprep(const float* __restrict__ x,
                                             const float* __restrict__ shape,
                                             const float* __restrict__ w_off,
                                             const float* __restrict__ w_def,
                                             float2* __restrict__ pos,
                                             u16* __restrict__ xT,
                                             u16* __restrict__ wF) {
    __shared__ __align__(16) float smem[64 * 65];
    int tid = threadIdx.x;
    int blk = blockIdx.x;

    if (blk < 2048) {
        // ---- kxt: x (B,256,H,W) fp32 -> xT[b][g][hw][c] bf16 ----
        float (*tile)[65] = (float (*)[65])smem;
        int bg  = blk >> 6;
        int hw0 = (blk & 63) << 6;
        int hwo = tid & 63;
#pragma unroll
        for (int i = 0; i < 16; ++i) {
            int c = (tid >> 6) + (i << 2);
            tile[c][hwo] = x[((bg << 6) + c) * HW + hw0 + hwo];
        }
        __syncthreads();
        int hw = tid >> 2;
        int cb4 = (tid & 3) << 4;
        short8 r0, r1;
#pragma unroll
        for (int j = 0; j < 8; ++j) {
            r0[j] = (short)f2bf(tile[cb4 + j][hw]);
            r1[j] = (short)f2bf(tile[cb4 + 8 + j][hw]);
        }
        u16* dst = xT + (((bg << 12) + hw0 + hw) << 6) + cb4;
        *(short8*)dst = r0;
        *(short8*)(dst + 8) = r1;
    } else if (blk < 4352) {
        // ---- kwb: fragment-major weights ----
        // element (gk, o, c) -> wF[gk][wid=o>>5][of=(o>>4)&1][kc=c>>5][lane=((c>>3)&3)<<4 | (o&15)][j=c&7]
        int idx = (blk - 2048) * 256 + tid;
        int c = idx & 63;
        int o = (idx >> 6) & 255;
        int gk = idx >> 14;
        int g = gk / 9, k = gk - g * 9;
        float v = w_def[((o << 8) + (g << 6) + c) * 9 + k];
        int wid = o >> 5, of = (o >> 4) & 1, olo = o & 15;
        int kc = c >> 5, cgran = (c >> 3) & 3, j = c & 7;
        int lane = (cgran << 4) | olo;
        wF[(gk << 14) + (wid << 11) + (of << 10) + (kc << 9) + (lane << 3) + j] = f2bf(v);
    } else {
        // ---- koff: sampling positions float2 [gk][pix] ----
        float* wo = smem;  // 72*36 floats
        for (int i = tid; i < 72 * 36; i += 256) wo[i] = w_off[i];
        __syncthreads();
        int pix = (blk - 4352) * 256 + tid;
        int b = pix >> 12, hw = pix & 4095;
        int h = hw >> 6, w = hw & 63;
        float s[36];
#pragma unroll
        for (int i = 0; i < 36; ++i) s[i] = shape[((b * 36 + i) << 12) + hw];
        for (int gk = 0; gk < 36; ++gk) {
            float oy = 0.f, ox = 0.f;
            const float* wy = &wo[(gk * 2 + 0) * 36];
            const float* wx = &wo[(gk * 2 + 1) * 36];
#pragma unroll
            for (int i = 0; i < 36; ++i) { oy += s[i] * wy[i]; ox += s[i] * wx[i]; }
            int k = gk % 9;
            pos[gk * NPIX + pix] = make_float2(oy + (float)(k / 3 - 1) + (float)h,
                                               ox + (float)(k % 3 - 1) + (float)w);
        }
    }
}

// ---------------- main: fused sampling + MFMA GEMM + ReLU ----------------
struct Samp {
    short8 v00, v01, v10, v11;
    float w00, w01, w10, w11;
    int dst;
};

__device__ __forceinline__ Samp sample_issue_p(float2 p, const u16* __restrict__ slab,
                                               int sp, int sck) {
    Samp s;
    float py = p.x, px = p.y;
    float y0f = floorf(py), x0f = floorf(px);
    float fy = py - y0f, fx = px - x0f;
    int y0 = (int)y0f, x0 = (int)x0f;
    int y1 = y0 + 1, x1 = x0 + 1;
    float vy0 = (y0 >= 0 && y0 < 64) ? 1.f : 0.f;
    float vy1 = (y1 >= 0 && y1 < 64) ? 1.f : 0.f;
    float vx0 = (x0 >= 0 && x0 < 64) ? 1.f : 0.f;
    float vx1 = (x1 >= 0 && x1 < 64) ? 1.f : 0.f;
    s.w00 = (1.f - fy) * (1.f - fx) * vy0 * vx0;
    s.w01 = (1.f - fy) * fx * vy0 * vx1;
    s.w10 = fy * (1.f - fx) * vy1 * vx0;
    s.w11 = fy * fx * vy1 * vx1;
    int yc0 = min(max(y0, 0), 63), yc1 = min(max(y1, 0), 63);
    int xc0 = min(max(x0, 0), 63), xc1 = min(max(x1, 0), 63);
    const u16* base = slab + (sck << 3);
    s.v00 = *(const short8*)(base + (((yc0 << 6) + xc0) << 6));
    s.v01 = *(const short8*)(base + (((yc0 << 6) + xc1) << 6));
    s.v10 = *(const short8*)(base + (((yc1 << 6) + xc0) << 6));
    s.v11 = *(const short8*)(base + (((yc1 << 6) + xc1) << 6));
    s.dst = (sp << 6) + ((sck ^ (sp & 7)) << 3);   // XOR-swizzled slot
    return s;
}

__device__ __forceinline__ void sample_finish(const Samp& s, u16* __restrict__ sVb) {
    union { short8 s8; u32 u[4]; } A, Bc, C, D;
    A.s8 = s.v00; Bc.s8 = s.v01; C.s8 = s.v10; D.s8 = s.v11;
    union { u32 u[4]; short8 s8; } R;
#pragma unroll
    for (int j = 0; j < 4; ++j) {
        float lo0 = fmaf(s.w00, bfu_lo(A.u[j]), s.w01 * bfu_lo(Bc.u[j]));
        float lo1 = fmaf(s.w10, bfu_lo(C.u[j]), s.w11 * bfu_lo(D.u[j]));
        float hi0 = fmaf(s.w00, bfu_hi(A.u[j]), s.w01 * bfu_hi(Bc.u[j]));
        float hi1 = fmaf(s.w10, bfu_hi(C.u[j]), s.w11 * bfu_hi(D.u[j]));
        __hip_bfloat162 pk = __float22bfloat162_rn(make_float2(lo0 + lo1, hi0 + hi1));
        union { __hip_bfloat162 b; u32 u; } cv; cv.b = pk;
        R.u[j] = cv.u;
    }
    *(short8*)(sVb + s.dst) = R.s8;
}

// MFMA over one tap: A-fragments (weights) already in registers, B from sV LDS.
__device__ __forceinline__ void mfma_phase(const short8 wcur[4], const u16* __restrict__ Vb,
                                           int lane, f32x4 acc[2][4]) {
    __builtin_amdgcn_s_setprio(1);
#pragma unroll
    for (int kc = 0; kc < 2; ++kc) {
        int cs = ((kc << 5) + ((lane >> 4) << 3)) ^ ((lane & 7) << 3);
        short8 bfr[4];
#pragma unroll
        for (int pf = 0; pf < 4; ++pf)
            bfr[pf] = *(const short8*)(Vb + (((pf << 4) + (lane & 15)) << 6) + cs);
#pragma unroll
        for (int of = 0; of < 2; ++of)
#pragma unroll
            for (int pf = 0; pf < 4; ++pf)
                acc[of][pf] = __builtin_amdgcn_mfma_f32_16x16x32_bf16(
                    wcur[of * 2 + kc], bfr[pf], acc[of][pf], 0, 0, 0);
    }
    __builtin_amdgcn_s_setprio(0);
}

__global__ __launch_bounds__(512, 4) void kmain(
    const u16* __restrict__ xT,
    const float2* __restrict__ pos,
    const u16* __restrict__ wF, float* __restrict__ out)
{
    __shared__ __align__(16) u16 sV[2][64 * 64];   // sampled values, 8KB each

    int tid = threadIdx.x;
    int pixbase = blockIdx.x << 6;   // 64 pixels per block
    int b = pixbase >> 12;

    int sp = tid >> 3, sck = tid & 7;        // sampling roles: 64px x 8 chunks
    int lane = tid & 63, wid = tid >> 6;     // compute roles
    int o0 = wid << 5;                       // 8 o-slices of 32 (no p-split)

    int pixw = pixbase + sp;
    const u16* slabB = xT + ((size_t)b << 20);   // 4 g-slabs of 4096px*64ch

    // fragment-major weight base for this (wid, lane): frag f at + f*512
    const u16* wlbase = wF + (wid << 11) + (lane << 3);

    f32x4 acc[2][4];
#pragma unroll
    for (int i = 0; i < 2; ++i)
#pragma unroll
        for (int j = 0; j < 4; ++j)
            acc[i][j] = (f32x4){0.f, 0.f, 0.f, 0.f};

    short8 wC[4], wN[4];   // [of*2+kc] weight fragments, current / next tap
    Samp s;
    float2 pv;

    // ---- prologue: weights tap0 -> wC; sample+finish tap0; pos for tap1 ----
    {
        wC[0] = *(const short8*)(wlbase);
        wC[1] = *(const short8*)(wlbase + 512);
        wC[2] = *(const short8*)(wlbase + 1024);
        wC[3] = *(const short8*)(wlbase + 1536);
        float2 pv0 = pos[pixw];
        Samp s0 = sample_issue_p(pv0, slabB, sp, sck);
        sample_finish(s0, sV[0]);
        pv = pos[NPIX + pixw];
        __syncthreads();
    }

    // body(t): prefetch weights(t+1)->WNXT (coalesced); issue gathers(t+1);
    // prefetch pos(t+2); MFMA(t) with WCUR + sV[t&1]; finish(t+1); barrier.
#define TAP_BODY(T, WCUR, WNXT)                                                  \
    {                                                                            \
        const int t_ = (T);                                                      \
        const u16* wn = wlbase + (t_ + 1) * WSTRIDE;                             \
        WNXT[0] = *(const short8*)(wn);                                          \
        WNXT[1] = *(const short8*)(wn + 512);                                    \
        WNXT[2] = *(const short8*)(wn + 1024);                                   \
        WNXT[3] = *(const short8*)(wn + 1536);                                   \
        s = sample_issue_p(pv, slabB + (((t_ + 1) / 9) << 18), sp, sck);         \
        pv = pos[(t_ + 2) * NPIX + pixw];                                        \
        __builtin_amdgcn_sched_barrier(0);                                       \
        mfma_phase(WCUR, sV[t_ & 1], lane, acc);                                 \
        sample_finish(s, sV[(t_ & 1) ^ 1]);                                      \
        __syncthreads();                                                         \
    }

    for (int t = 0; t < 34; t += 2) {
        TAP_BODY(t,     wC, wN)
        TAP_BODY(t + 1, wN, wC)
    }
#undef TAP_BODY

    // ---- t=34: uses wC (loaded in body 33); prefetch tap35 -> wN; finish 35 ----
    {
        const u16* wn = wlbase + 35 * WSTRIDE;
        wN[0] = *(const short8*)(wn);
        wN[1] = *(const short8*)(wn + 512);
        wN[2] = *(const short8*)(wn + 1024);
        wN[3] = *(const short8*)(wn + 1536);
        s = sample_issue_p(pv, slabB + (3 << 18), sp, sck);
        __builtin_amdgcn_sched_barrier(0);
        mfma_phase(wC, sV[0], lane, acc);
        sample_finish(s, sV[1]);
        __syncthreads();
    }
    // ---- t=35 ----
    mfma_phase(wN, sV[1], lane, acc);

    // ---- epilogue: ReLU + store ----
    int hwb = pixbase & 4095;
    int obase = (b << 8) + o0 + ((lane >> 4) << 2);
#pragma unroll
    for (int of = 0; of < 2; ++of) {
#pragma unroll
        for (int pf = 0; pf < 4; ++pf) {
            float* op = out + ((obase + (of << 4)) << 12) + hwb + (pf << 4) + (lane & 15);
#pragma unroll
            for (int r = 0; r < 4; ++r)
                op[r << 12] = fmaxf(acc[of][pf][r], 0.f);
        }
    }
}

extern "C" void kernel_launch(void* const* d_in, const int* in_sizes, int n_in,
                              void* d_out, int out_size, void* d_ws, size_t ws_size,
                              hipStream_t stream) {
    const float* x     = (const float*)d_in[0];
    const float* shape = (const float*)d_in[1];
    const float* w_off = (const float*)d_in[2];
    const float* w_def = (const float*)d_in[3];
    float* out = (float*)d_out;

    float2* pos = (float2*)d_ws;                      // 36*32768 float2 = 9.4 MB
    u16*    wF  = (u16*)(pos + NGK * NPIX);           // 36*256*64 bf16 = 1.18 MB
    u16*    xT  = wF + NGK * 256 * 64;                // 8*4*4096*64 bf16 = 16.8 MB

    kprep<<<4480, 256, 0, stream>>>(x, shape, w_off, w_def, pos, xT, wF);
    kmain<<<NPIX / 64, 512, 0, stream>>>(xT, pos, wF, out);
}

// Round 8
// 86.061 us; speedup vs baseline: 2.7463x; 1.1774x over previous
//
#include <hip/hip_runtime.h>
#include <hip/hip_bf16.h>

// FeatureAdaption on MI355X: offset = shape @ w_off (1x1), DCNv1 deform conv + ReLU.
// B=8, Cin=Cout=256, H=W=64, G=4, Cg=64, K=3, K2=9, NGK=36, NPIX=32768.
// kprep (merged, koff FIRST): pos (float2), channels-last bf16 xT[b][g][hw][c],
// fragment-major bf16 weights wF. kmain: 256o x 64px tile, 512 blocks (2/CU);
// per-block LDS rec tables (corner addrs + f32 weights computed ONCE per (gk,px));
// weights global->register fragments one tap ahead; sV double-buffer (16 KB).

#define NPIX 32768
#define NGK  36
#define HW   4096
#define WSTRIDE 16384   // u16 elements per tap in wF

typedef __attribute__((ext_vector_type(8))) short short8;
typedef __attribute__((ext_vector_type(4))) float f32x4;
typedef unsigned short u16;
typedef unsigned int u32;

__device__ __forceinline__ float bfu_lo(u32 u) {
    union { u32 u; float f; } cv; cv.u = u << 16; return cv.f;
}
__device__ __forceinline__ float bfu_hi(u32 u) {
    union { u32 u; float f; } cv; cv.u = u & 0xFFFF0000u; return cv.f;
}
__device__ __forceinline__ u16 f2bf(float f) {
    union { float f; u32 u; } cv;
    cv.f = f;
    u32 u = cv.u + 0x7FFFu + ((cv.u >> 16) & 1u);
    return (u16)(u >> 16);
}

// ---------------- kprep: koff (128) + kxt (2048) + kwb (2304) ----------------
__global__ __launch_bounds__(256) void kprep(const float* __restrict__ x,
                                             const float* __restrict__ shape,
                                             const float* __restrict__ w_off,
                                             const float* __restrict__ w_def,
                                             float2* __restrict__ pos,
                                             u16* __restrict__ xT,
                                             u16* __restrict__ wF) {
    __shared__ __align__(16) float smem[64 * 65];
    int tid = threadIdx.x;
    int blk = blockIdx.x;

    if (blk < 128) {
        // ---- koff: sampling positions float2 [gk][pix] (heavy -> launch first) ----
        float* wo = smem;  // 72*36 floats
        for (int i = tid; i < 72 * 36; i += 256) wo[i] = w_off[i];
        __syncthreads();
        int pix = blk * 256 + tid;
        int b = pix >> 12, hw = pix & 4095;
        int h = hw >> 6, w = hw & 63;
        float s[36];
#pragma unroll
        for (int i = 0; i < 36; ++i) s[i] = shape[((b * 36 + i) << 12) + hw];
        for (int gk = 0; gk < 36; ++gk) {
            float oy = 0.f, ox = 0.f;
            const float* wy = &wo[(gk * 2 + 0) * 36];
            const float* wx = &wo[(gk * 2 + 1) * 36];
#pragma unroll
            for (int i = 0; i < 36; ++i) { oy += s[i] * wy[i]; ox += s[i] * wx[i]; }
            int k = gk % 9;
            pos[gk * NPIX + pix] = make_float2(oy + (float)(k / 3 - 1) + (float)h,
                                               ox + (float)(k % 3 - 1) + (float)w);
        }
    } else if (blk < 2176) {
        // ---- kxt: x (B,256,H,W) fp32 -> xT[b][g][hw][c] bf16 ----
        float (*tile)[65] = (float (*)[65])smem;
        int xb  = blk - 128;
        int bg  = xb >> 6;
        int hw0 = (xb & 63) << 6;
        int hwo = tid & 63;
#pragma unroll
        for (int i = 0; i < 16; ++i) {
            int c = (tid >> 6) + (i << 2);
            tile[c][hwo] = x[((bg << 6) + c) * HW + hw0 + hwo];
        }
        __syncthreads();
        int hw = tid >> 2;
        int cb4 = (tid & 3) << 4;
        short8 r0, r1;
#pragma unroll
        for (int j = 0; j < 8; ++j) {
            r0[j] = (short)f2bf(tile[cb4 + j][hw]);
            r1[j] = (short)f2bf(tile[cb4 + 8 + j][hw]);
        }
        u16* dst = xT + (((bg << 12) + hw0 + hw) << 6) + cb4;
        *(short8*)dst = r0;
        *(short8*)(dst + 8) = r1;
    } else {
        // ---- kwb: fragment-major weights ----
        // (gk,o,c) -> wF[gk][wid=o>>5][of=(o>>4)&1][kc=c>>5][lane=((c>>3)&3)<<4|(o&15)][j=c&7]
        int idx = (blk - 2176) * 256 + tid;
        int c = idx & 63;
        int o = (idx >> 6) & 255;
        int gk = idx >> 14;
        int g = gk / 9, k = gk - g * 9;
        float v = w_def[((o << 8) + (g << 6) + c) * 9 + k];
        int wid = o >> 5, of = (o >> 4) & 1, olo = o & 15;
        int kc = c >> 5, cgran = (c >> 3) & 3, j = c & 7;
        int lane = (cgran << 4) | olo;
        wF[(gk << 14) + (wid << 11) + (of << 10) + (kc << 9) + (lane << 3) + j] = f2bf(v);
    }
}

// ---------------- main: fused sampling + MFMA GEMM + ReLU ----------------
struct Samp {
    short8 v00, v01, v10, v11;
    float w00, w01, w10, w11;
    int dst;
};

__device__ __forceinline__ Samp sample_issue_rec(uint2 ra, float4 rw,
                                                 const u16* __restrict__ slab,
                                                 int sp, int sck) {
    Samp s;
    int a00 = ra.x & 0xFFFF, a01 = ra.x >> 16;
    int a10 = ra.y & 0xFFFF, a11 = ra.y >> 16;
    const u16* base = slab + (sck << 3);
    s.v00 = *(const short8*)(base + (a00 << 6));
    s.v01 = *(const short8*)(base + (a01 << 6));
    s.v10 = *(const short8*)(base + (a10 << 6));
    s.v11 = *(const short8*)(base + (a11 << 6));
    s.w00 = rw.x; s.w01 = rw.y; s.w10 = rw.z; s.w11 = rw.w;
    s.dst = (sp << 6) + ((sck ^ (sp & 7)) << 3);   // XOR-swizzled slot
    return s;
}

__device__ __forceinline__ void sample_finish(const Samp& s, u16* __restrict__ sVb) {
    union { short8 s8; u32 u[4]; } A, Bc, C, D;
    A.s8 = s.v00; Bc.s8 = s.v01; C.s8 = s.v10; D.s8 = s.v11;
    union { u32 u[4]; short8 s8; } R;
#pragma unroll
    for (int j = 0; j < 4; ++j) {
        float lo0 = fmaf(s.w00, bfu_lo(A.u[j]), s.w01 * bfu_lo(Bc.u[j]));
        float lo1 = fmaf(s.w10, bfu_lo(C.u[j]), s.w11 * bfu_lo(D.u[j]));
        float hi0 = fmaf(s.w00, bfu_hi(A.u[j]), s.w01 * bfu_hi(Bc.u[j]));
        float hi1 = fmaf(s.w10, bfu_hi(C.u[j]), s.w11 * bfu_hi(D.u[j]));
        __hip_bfloat162 pk = __float22bfloat162_rn(make_float2(lo0 + lo1, hi0 + hi1));
        union { __hip_bfloat162 b; u32 u; } cv; cv.b = pk;
        R.u[j] = cv.u;
    }
    *(short8*)(sVb + s.dst) = R.s8;
}

// MFMA over one tap: A-fragments (weights) in registers, B from sV LDS.
__device__ __forceinline__ void mfma_phase(const short8 wcur[4], const u16* __restrict__ Vb,
                                           int lane, f32x4 acc[2][4]) {
    __builtin_amdgcn_s_setprio(1);
#pragma unroll
    for (int kc = 0; kc < 2; ++kc) {
        int cs = ((kc << 5) + ((lane >> 4) << 3)) ^ ((lane & 7) << 3);
        short8 bfr[4];
#pragma unroll
        for (int pf = 0; pf < 4; ++pf)
            bfr[pf] = *(const short8*)(Vb + (((pf << 4) + (lane & 15)) << 6) + cs);
#pragma unroll
        for (int of = 0; of < 2; ++of)
#pragma unroll
            for (int pf = 0; pf < 4; ++pf)
                acc[of][pf] = __builtin_amdgcn_mfma_f32_16x16x32_bf16(
                    wcur[of * 2 + kc], bfr[pf], acc[of][pf], 0, 0, 0);
    }
    __builtin_amdgcn_s_setprio(0);
}

__global__ __launch_bounds__(512, 4) void kmain(
    const u16* __restrict__ xT,
    const float2* __restrict__ pos,
    const u16* __restrict__ wF, float* __restrict__ out)
{
    __shared__ __align__(16) u16 sV[2][64 * 64];     // sampled values, 8KB each
    __shared__ __align__(16) uint2 sRA[NGK * 64];    // packed corner addrs, 18 KB
    __shared__ __align__(16) float4 sRW[NGK * 64];   // corner weights f32, 36 KB

    int tid = threadIdx.x;
    int pixbase = blockIdx.x << 6;   // 64 pixels per block
    int b = pixbase >> 12;

    int sp = tid >> 3, sck = tid & 7;        // sampling roles: 64px x 8 chunks
    int lane = tid & 63, wid = tid >> 6;     // compute roles
    int o0 = wid << 5;                       // 8 o-slices of 32

    const u16* slabB = xT + ((size_t)b << 20);   // 4 g-slabs of 4096px*64ch
    const u16* wlbase = wF + (wid << 11) + (lane << 3);

    f32x4 acc[2][4];
#pragma unroll
    for (int i = 0; i < 2; ++i)
#pragma unroll
        for (int j = 0; j < 4; ++j)
            acc[i][j] = (f32x4){0.f, 0.f, 0.f, 0.f};

    short8 wC[4], wN[4];
    Samp s;

    // ---- prologue A: build rec tables (once per block: 36 taps x 64 px) ----
    for (int i = tid; i < NGK * 64; i += 512) {
        int gk = i >> 6, px = i & 63;
        float2 p = pos[gk * NPIX + pixbase + px];
        float py = p.x, pxx = p.y;
        float y0f = floorf(py), x0f = floorf(pxx);
        float fy = py - y0f, fx = pxx - x0f;
        int y0 = (int)y0f, x0 = (int)x0f;
        int y1 = y0 + 1, x1 = x0 + 1;
        float vy0 = (y0 >= 0 && y0 < 64) ? 1.f : 0.f;
        float vy1 = (y1 >= 0 && y1 < 64) ? 1.f : 0.f;
        float vx0 = (x0 >= 0 && x0 < 64) ? 1.f : 0.f;
        float vx1 = (x1 >= 0 && x1 < 64) ? 1.f : 0.f;
        float w00 = (1.f - fy) * (1.f - fx) * vy0 * vx0;
        float w01 = (1.f - fy) * fx * vy0 * vx1;
        float w10 = fy * (1.f - fx) * vy1 * vx0;
        float w11 = fy * fx * vy1 * vx1;
        int yc0 = min(max(y0, 0), 63), yc1 = min(max(y1, 0), 63);
        int xc0 = min(max(x0, 0), 63), xc1 = min(max(x1, 0), 63);
        u32 A = (u32)((yc0 << 6) | xc0) | ((u32)((yc0 << 6) | xc1) << 16);
        u32 Bp = (u32)((yc1 << 6) | xc0) | ((u32)((yc1 << 6) | xc1) << 16);
        sRA[i] = make_uint2(A, Bp);
        sRW[i] = make_float4(w00, w01, w10, w11);
    }

    // weights tap0 -> wC (independent of rec tables)
    wC[0] = *(const short8*)(wlbase);
    wC[1] = *(const short8*)(wlbase + 512);
    wC[2] = *(const short8*)(wlbase + 1024);
    wC[3] = *(const short8*)(wlbase + 1536);
    __syncthreads();   // rec tables ready

    // ---- prologue B: sample + finish tap 0 ----
    {
        Samp s0 = sample_issue_rec(sRA[sp], sRW[sp], slabB, sp, sck);
        sample_finish(s0, sV[0]);
    }
    __syncthreads();

    // body(t): weights(t+1)->WNXT; rec(t+1) from LDS; issue gathers(t+1);
    // MFMA(t) with WCUR + sV[t&1]; finish(t+1) -> sV[nb]; barrier.
#define TAP_BODY(T, WCUR, WNXT)                                                  \
    {                                                                            \
        const int t_ = (T);                                                      \
        const u16* wn = wlbase + (t_ + 1) * WSTRIDE;                             \
        WNXT[0] = *(const short8*)(wn);                                          \
        WNXT[1] = *(const short8*)(wn + 512);                                    \
        WNXT[2] = *(const short8*)(wn + 1024);                                   \
        WNXT[3] = *(const short8*)(wn + 1536);                                   \
        s = sample_issue_rec(sRA[((t_ + 1) << 6) + sp], sRW[((t_ + 1) << 6) + sp], \
                             slabB + (((t_ + 1) / 9) << 18), sp, sck);           \
        __builtin_amdgcn_sched_barrier(0);                                       \
        mfma_phase(WCUR, sV[t_ & 1], lane, acc);                                 \
        sample_finish(s, sV[(t_ & 1) ^ 1]);                                      \
        __syncthreads();                                                         \
    }

    for (int t = 0; t < 34; t += 2) {
        TAP_BODY(t,     wC, wN)
        TAP_BODY(t + 1, wN, wC)
    }
#undef TAP_BODY

    // ---- t=34: uses wC; prefetch tap35 -> wN; finish tap35 samples ----
    {
        const u16* wn = wlbase + 35 * WSTRIDE;
        wN[0] = *(const short8*)(wn);
        wN[1] = *(const short8*)(wn + 512);
        wN[2] = *(const short8*)(wn + 1024);
        wN[3] = *(const short8*)(wn + 1536);
        s = sample_issue_rec(sRA[(35 << 6) + sp], sRW[(35 << 6) + sp],
                             slabB + (3 << 18), sp, sck);
        __builtin_amdgcn_sched_barrier(0);
        mfma_phase(wC, sV[0], lane, acc);
        sample_finish(s, sV[1]);
        __syncthreads();
    }
    // ---- t=35 ----
    mfma_phase(wN, sV[1], lane, acc);

    // ---- epilogue: ReLU + store ----
    int hwb = pixbase & 4095;
    int obase = (b << 8) + o0 + ((lane >> 4) << 2);
#pragma unroll
    for (int of = 0; of < 2; ++of) {
#pragma unroll
        for (int pf = 0; pf < 4; ++pf) {
            float* op = out + ((obase + (of << 4)) << 12) + hwb + (pf << 4) + (lane & 15);
#pragma unroll
            for (int r = 0; r < 4; ++r)
                op[r << 12] = fmaxf(acc[of][pf][r], 0.f);
        }
    }
}

extern "C" void kernel_launch(void* const* d_in, const int* in_sizes, int n_in,
                              void* d_out, int out_size, void* d_ws, size_t ws_size,
                              hipStream_t stream) {
    const float* x     = (const float*)d_in[0];
    const float* shape = (const float*)d_in[1];
    const float* w_off = (const float*)d_in[2];
    const float* w_def = (const float*)d_in[3];
    float* out = (float*)d_out;

    float2* pos = (float2*)d_ws;                      // 36*32768 float2 = 9.4 MB
    u16*    wF  = (u16*)(pos + NGK * NPIX);           // 36*256*64 bf16 = 1.18 MB
    u16*    xT  = wF + NGK * 256 * 64;                // 8*4*4096*64 bf16 = 16.8 MB

    kprep<<<4480, 256, 0, stream>>>(x, shape, w_off, w_def, pos, xT, wF);
    kmain<<<NPIX / 64, 512, 0, stream>>>(xT, pos, wF, out);
}